// Round 5
// baseline (127.066 us; speedup 1.0000x reference)
//
#include <hip/hip_runtime.h>
#include <math.h>

#define HID 2880
#define NE  128
#define BK  32              // k per chunk
#define TOKB 64
#define NCHG 30             // chunks per ks-group (3 groups x 30 = 90)
#define PSTR 129

typedef _Float16 half8v __attribute__((ext_vector_type(8)));
typedef float    f32x4v __attribute__((ext_vector_type(4)));

// ---------------- prep: split W fp32 -> f16 hi/lo, [chunk 90][e 128][k 32] ------
__global__ __launch_bounds__(256)
void prep_w(const float* __restrict__ W, _Float16* __restrict__ whi,
            _Float16* __restrict__ wlo)
{
    const int e = blockIdx.x;
    for (int j = 0; j < 12; ++j) {
        const int k = j * 256 + threadIdx.x;
        if (k >= HID) break;
        const float v = W[(size_t)e * HID + k];
        const _Float16 h = (_Float16)v;
        const _Float16 l = (_Float16)(v - (float)h);
        const size_t idx = (size_t)(k >> 5) * 4096 + e * 32 + (k & 31);
        whi[idx] = h;
        wlo[idx] = l;
    }
}

// asm-forced 16B global load: regs cannot be collapsed/sunk; order = issue order.
#define GLOAD(dst, ptr) \
    asm volatile("global_load_dwordx4 %0, %1, off" : "=v"(dst) : "v"(ptr))
#define GLOAD_O16(dst, ptr) \
    asm volatile("global_load_dwordx4 %0, %1, off offset:16" : "=v"(dst) : "v"(ptr))
#define GLOAD_O1024(dst, ptr) \
    asm volatile("global_load_dwordx4 %0, %1, off offset:1024" : "=v"(dst) : "v"(ptr))

// ---------------- fused: 12-wave 3-way k-split, NO LDS STAGING, no barriers -------
// R4 lesson: four schedules of the staged-LDS/barrier dataflow all land at 65-67us
// => the dataflow is the bottleneck. The 16x16x32 B-operand fragment is lane-local
// in A's row-major layout (lane l: token l&15, 8 consecutive k at (l>>4)*8), so
// each lane loads its fragment DIRECTLY from global (2 dwordx4), converts f32->
// f16 hi/lo in-register, and feeds MFMA. No LDS, no CONVA publish, no barriers:
// waves are fully self-paced; 3 waves/SIMD TLP hides memory latency. A-tile is
// read 4x (once per wq-wave) but the 8KB chunk window is L1/L2-hot. Per-chunk
// register double-buffer (8 A + 4 W dwordx4), VMC(12) per chunk (never 0
// mid-loop). MFMA values and order bit-identical to R0-R4.
__global__ __launch_bounds__(768, 3)
void fused_router(const float* __restrict__ A, const _Float16* __restrict__ whi,
                  const _Float16* __restrict__ wlo, const float* __restrict__ bias,
                  float* __restrict__ scores, float* __restrict__ idxOut,
                  float* __restrict__ counts)
{
    // LDS: epilogue only. P1 33024 + P2 33024 + cval 8448 + cidx 8448 = 82944 B
    __shared__ __align__(16) char smem[82944];
    __shared__ float sval[TOKB][4];
    __shared__ int   sidx[TOKB][4];
    __shared__ int   hist[NE];

    const int tid  = threadIdx.x;
    const int lane = tid & 63;
    const int wv   = __builtin_amdgcn_readfirstlane(tid >> 6);   // 0..11
    const int ks   = wv >> 2;        // k-third 0..2
    const int wq   = wv & 3;         // expert group 0..3
    const int lg   = lane >> 4;      // k-quarter 0..3
    const int lr   = lane & 15;
    const int tokBase = blockIdx.x * TOKB;
    const int hbeg = ks * NCHG;      // first global chunk of this k-third

    // W per-lane fragment pointers (m=0): e = wq*32 + lr, k-off lg*8;
    // m=1 (+16 experts) = +1024 B immediate. Advance 4096 halves per chunk.
    const _Float16* wHp = whi + (size_t)((wq * 32 + lr) * 32 + lg * 8)
                        + (size_t)hbeg * 4096;
    const _Float16* wLp = wlo + (size_t)((wq * 32 + lr) * 32 + lg * 8)
                        + (size_t)hbeg * 4096;

    // A fragment pointers: frag n -> token tokBase + n*16 + lr, k = ks*960 + lg*8.
    // Each lane reads 8 consecutive f32 (2 dwordx4) = its B-operand fragment.
    const float* aP[4];
#pragma unroll
    for (int n = 0; n < 4; ++n)
        aP[n] = A + (size_t)(tokBase + n * 16 + lr) * HID + ks * 960 + lg * 8;

    // issue one chunk of A into BUF (8 dwordx4) and advance pointers
#define AISSUE(BUF) do {                                                       \
    _Pragma("unroll")                                                          \
    for (int n = 0; n < 4; ++n) {                                              \
        GLOAD(BUF[2 * n],     aP[n]);                                          \
        GLOAD_O16(BUF[2 * n + 1], aP[n]);                                      \
        aP[n] += BK;                                                           \
    }                                                                          \
} while (0)

    // issue one chunk of W into WS (4 dwordx4) and advance pointers
#define WISSUE(WS) do {                                                        \
    GLOAD(WS[0], wHp);                                                         \
    GLOAD(WS[1], wLp);                                                         \
    GLOAD_O1024(WS[2], wHp);                                                   \
    GLOAD_O1024(WS[3], wLp);                                                   \
    wHp += 4096;                                                               \
    wLp += 4096;                                                               \
} while (0)

#define VMC(n) do {                                                            \
    asm volatile("s_waitcnt vmcnt(" #n ")" ::: "memory");                      \
    __builtin_amdgcn_sched_barrier(0);                                         \
} while (0)

    f32x4v acc[2][4];
#pragma unroll
    for (int m = 0; m < 2; ++m)
#pragma unroll
        for (int n = 0; n < 4; ++n) acc[m][n] = (f32x4v)0.f;

    float4 a0[8], a1[8];
    half8v w0[4], w1[4];

    // chunk body: retire this chunk's 12 loads (keep next chunk's 12 in flight),
    // convert per frag in-register (bit-identical ops to CONVA1), 24 MFMAs in
    // the same order as R0-R4's CCHUNK, then reissue this buffer for chunk c+2.
#define CHUNK(ABUF, WBUF, DOISSUE, VMN) do {                                   \
    VMC(VMN);                                                                  \
    _Pragma("unroll")                                                          \
    for (int n = 0; n < 4; ++n) {                                              \
        const float4 u = ABUF[2 * n], v = ABUF[2 * n + 1];                     \
        const _Float16 h0=(_Float16)u.x, h1=(_Float16)u.y,                     \
                       h2=(_Float16)u.z, h3=(_Float16)u.w;                     \
        const _Float16 h4=(_Float16)v.x, h5=(_Float16)v.y,                     \
                       h6=(_Float16)v.z, h7=(_Float16)v.w;                     \
        const half8v ah = {h0,h1,h2,h3,h4,h5,h6,h7};                           \
        const half8v al = {(_Float16)(u.x-(float)h0),(_Float16)(u.y-(float)h1),\
                           (_Float16)(u.z-(float)h2),(_Float16)(u.w-(float)h3),\
                           (_Float16)(v.x-(float)h4),(_Float16)(v.y-(float)h5),\
                           (_Float16)(v.z-(float)h6),(_Float16)(v.w-(float)h7)};\
        _Pragma("unroll")                                                      \
        for (int m = 0; m < 2; ++m) {                                          \
            acc[m][n] = __builtin_amdgcn_mfma_f32_16x16x32_f16(                \
                WBUF[m * 2 + 0], ah, acc[m][n], 0, 0, 0);                      \
            acc[m][n] = __builtin_amdgcn_mfma_f32_16x16x32_f16(                \
                WBUF[m * 2 + 1], ah, acc[m][n], 0, 0, 0);                      \
            acc[m][n] = __builtin_amdgcn_mfma_f32_16x16x32_f16(                \
                WBUF[m * 2 + 0], al, acc[m][n], 0, 0, 0);                      \
        }                                                                      \
    }                                                                          \
    if (DOISSUE) { AISSUE(ABUF); WISSUE(WBUF); }                               \
} while (0)

    // prologue: chunks 0,1 in flight (12 loads each, A-then-W grouping)
    AISSUE(a0); WISSUE(w0);
    AISSUE(a1); WISSUE(w1);

    // chunks 0..27 in pairs; each body issues chunk c+2 into its own buffer
#pragma unroll 1
    for (int c2 = 0; c2 < 28; c2 += 2) {
        CHUNK(a0, w0, 1, 12);
        CHUNK(a1, w1, 1, 12);
    }
    CHUNK(a0, w0, 0, 12);   // chunk 28 (29's loads stay in flight)
    CHUNK(a1, w1, 0, 0);    // chunk 29 (drain)

    // ---------------- epilogue: deterministic 3-way reduction ----------------
    float* P1   = (float*)(smem);            // 64*129*4 = 33024 B
    float* P2   = (float*)(smem + 33024);    // 33024 B
    float* cval = (float*)(smem + 66048);    // 64*33*4 = 8448 B
    int*   cidx = (int*)(smem + 74496);      // 8448 B

    if (tid < NE) hist[tid] = 0;

    // ks=1/2 partials -> LDS
    if (ks == 1 || ks == 2) {
        float* P = (ks == 1) ? P1 : P2;
#pragma unroll
        for (int m = 0; m < 2; ++m)
#pragma unroll
            for (int n = 0; n < 4; ++n)
#pragma unroll
                for (int r = 0; r < 4; ++r) {
                    const int e = wq * 32 + m * 16 + lg * 4 + r;
                    const int t = n * 16 + lr;
                    P[t * PSTR + e] = acc[m][n][r];
                }
    }
    __syncthreads();

    // ks=0 combines in fixed order -> logits in P1
    if (ks == 0) {
#pragma unroll
        for (int m = 0; m < 2; ++m)
#pragma unroll
            for (int n = 0; n < 4; ++n)
#pragma unroll
                for (int r = 0; r < 4; ++r) {
                    const int e = wq * 32 + m * 16 + lg * 4 + r;
                    const int t = n * 16 + lr;
                    const int off = t * PSTR + e;
                    P1[off] = ((acc[m][n][r] + P1[off]) + P2[off]) + bias[e];
                }
    }
    __syncthreads();

    // top-4 candidates: 64 tok x 8 groups of 16 experts (threads 0..511)
    if (tid < 512) {
        const int t = tid & 63, g = tid >> 6;
        float v0 = -1e30f, v1 = -1e30f, v2 = -1e30f, v3 = -1e30f;
        int   i0 = 0, i1 = 0, i2 = 0, i3 = 0;
        const int e0 = g * 16;
#pragma unroll 4
        for (int i = 0; i < 16; ++i) {
            const int e = e0 + i;
            const float v = P1[t * PSTR + e];
            if (v > v3) {
                if (v > v2) {
                    v3 = v2; i3 = i2;
                    if (v > v1) {
                        v2 = v1; i2 = i1;
                        if (v > v0) { v1 = v0; i1 = i0; v0 = v; i0 = e; }
                        else        { v1 = v;  i1 = e; }
                    } else { v2 = v; i2 = e; }
                } else { v3 = v; i3 = e; }
            }
        }
        cval[t * 33 + g * 4 + 0] = v0; cidx[t * 33 + g * 4 + 0] = i0;
        cval[t * 33 + g * 4 + 1] = v1; cidx[t * 33 + g * 4 + 1] = i1;
        cval[t * 33 + g * 4 + 2] = v2; cidx[t * 33 + g * 4 + 2] = i2;
        cval[t * 33 + g * 4 + 3] = v3; cidx[t * 33 + g * 4 + 3] = i3;
    }
    __syncthreads();

    if (tid < TOKB) {
        const int t = tid;
        float m0 = -1e30f, m1 = -1e30f, m2 = -1e30f, m3 = -1e30f;
        int   j0 = 0, j1 = 0, j2 = 0, j3 = 0;
#pragma unroll
        for (int q = 0; q < 32; ++q) {   // group-major, ascending e within group
            const float v = cval[t * 33 + q];
            const int   e = cidx[t * 33 + q];
            if (v > m3) {
                if (v > m2) {
                    m3 = m2; j3 = j2;
                    if (v > m1) {
                        m2 = m1; j2 = j1;
                        if (v > m0) { m1 = m0; j1 = j0; m0 = v; j0 = e; }
                        else        { m1 = v;  j1 = e; }
                    } else { m2 = v; j2 = e; }
                } else { m3 = v; j3 = e; }
            }
        }
        const float x1 = expf(m1 - m0), x2 = expf(m2 - m0), x3 = expf(m3 - m0);
        const float inv = 1.f / (1.f + x1 + x2 + x3);
        sval[t][0] = inv;      sidx[t][0] = j0;
        sval[t][1] = x1 * inv; sidx[t][1] = j1;
        sval[t][2] = x2 * inv; sidx[t][2] = j2;
        sval[t][3] = x3 * inv; sidx[t][3] = j3;
        atomicAdd(&hist[j0], 1); atomicAdd(&hist[j1], 1);
        atomicAdd(&hist[j2], 1); atomicAdd(&hist[j3], 1);
    }
    __syncthreads();

    // dense score scatter: 64 tok x 128 exp = 8192 floats, coalesced
    const size_t sBase = (size_t)blockIdx.x * TOKB * NE;
#pragma unroll 4
    for (int it = 0; it < 11; ++it) {
        const int flat = it * 768 + tid;
        if (flat < TOKB * NE) {
            const int t = flat >> 7, e = flat & 127;
            float val = 0.f;
            val = (e == sidx[t][0]) ? sval[t][0] : val;
            val = (e == sidx[t][1]) ? sval[t][1] : val;
            val = (e == sidx[t][2]) ? sval[t][2] : val;
            val = (e == sidx[t][3]) ? sval[t][3] : val;
            scores[sBase + flat] = val;
        }
    }
    // indices as float32: 256 per block
    if (tid < TOKB * 4)
        idxOut[(size_t)blockIdx.x * TOKB * 4 + tid] =
            (float)sidx[tid >> 2][tid & 3];
    if (tid < NE) {
        const int c = hist[tid];
        if (c) atomicAdd(&counts[tid], (float)c);
    }
#undef AISSUE
#undef WISSUE
#undef VMC
#undef CHUNK
}

extern "C" void kernel_launch(void* const* d_in, const int* in_sizes, int n_in,
                              void* d_out, int out_size, void* d_ws, size_t ws_size,
                              hipStream_t stream) {
    const float* A = (const float*)d_in[0];   // hidden_states [T, 2880]
    const float* W = (const float*)d_in[1];   // weight [128, 2880]
    const float* B = (const float*)d_in[2];   // bias [128]
    const int T = in_sizes[0] / HID;          // 16384

    float* out = (float*)d_out;
    float* scores = out;                          // [T,128]
    float* idxOut = out + (size_t)T * NE;         // [T,4] as float
    float* counts = idxOut + (size_t)T * 4;       // [128] as float

    _Float16* whi = (_Float16*)d_ws;              // [90][128][32] halves
    _Float16* wlo = whi + (size_t)NE * HID;

    hipMemsetAsync(counts, 0, NE * sizeof(float), stream);

    hipLaunchKernelGGL(prep_w, dim3(NE), dim3(256), 0, stream, W, whi, wlo);
    hipLaunchKernelGGL(fused_router, dim3(T / TOKB), dim3(768), 0, stream,
                       A, whi, wlo, B, scores, idxOut, counts);
}

// Round 6
// 73.980 us; speedup vs baseline: 1.7176x; 1.7176x over previous
//
#include <hip/hip_runtime.h>
#include <math.h>

#define HID 2880
#define NE  128
#define BK  32              // k per chunk
#define TOKB 64
#define NCHG 30             // chunks per ks-group (3 groups x 30 = 90)
#define PSTR 129

typedef _Float16 half8v __attribute__((ext_vector_type(8)));
typedef float    f32x4v __attribute__((ext_vector_type(4)));

// ---------------- prep: split W fp32 -> f16 hi/lo, [chunk 90][e 128][k 32] ------
__global__ __launch_bounds__(256)
void prep_w(const float* __restrict__ W, _Float16* __restrict__ whi,
            _Float16* __restrict__ wlo)
{
    const int e = blockIdx.x;
    for (int j = 0; j < 12; ++j) {
        const int k = j * 256 + threadIdx.x;
        if (k >= HID) break;
        const float v = W[(size_t)e * HID + k];
        const _Float16 h = (_Float16)v;
        const _Float16 l = (_Float16)(v - (float)h);
        const size_t idx = (size_t)(k >> 5) * 4096 + e * 32 + (k & 31);
        whi[idx] = h;
        wlo[idx] = l;
    }
}

// asm-forced 16B global load: regs cannot be collapsed/sunk; order = issue order.
#define GLOAD(dst, ptr) \
    asm volatile("global_load_dwordx4 %0, %1, off" : "=v"(dst) : "v"(ptr))
#define GLOAD_O1024(dst, ptr) \
    asm volatile("global_load_dwordx4 %0, %1, off offset:1024" : "=v"(dst) : "v"(ptr))

// ---------------- fused: 12-wave 3-way k-split, per-chunk CELL schedule -----------
// R5 synthesis: all 2-phase schedules (big mem phase -> drain -> big compute ->
// barrier) pin at 65-67us regardless of barrier count / FIFO order — the m233
// "2-phase structural overhead" signature (and our r1 swizzle-null matches the
// documented T2-null-at-2ph gate). This version ports the 8-phase cell
// structure (T3+T4+T5): 30 cells, one chunk each:
//   mem-half: [c%3==0: ASTAGE(g+1)] [c%3==2: VMC(8): retire W(c)+A; CONVA g+1]
//             [else: VMC(14): retire W(c) only] + ds_read chunk c (8 b128)
//   s_barrier ; lgkmcnt(0) ; setprio(1) 24 MFMA setprio(0) ; WISSUE W(c+3)
//   s_barrier
// Loads span 3 cells; in-flight never below 8 mid-loop (counted vmcnt ledger);
// each W set is refilled immediately AFTER its MFMAs consume it. MFMA cluster
// is pure-register between barriers. Numerics bit-identical to R0-R4.
__global__ __launch_bounds__(768, 3)
void fused_router(const float* __restrict__ A, const _Float16* __restrict__ whi,
                  const _Float16* __restrict__ wlo, const float* __restrict__ bias,
                  float* __restrict__ scores, float* __restrict__ idxOut,
                  float* __restrict__ counts)
{
    // ring: [ks 3][slot 6][h 2][64 tok][32 k f16] = 3*6*8192 = 147456 B
    __shared__ __align__(16) char smem[147456];
    __shared__ float sval[TOKB][4];
    __shared__ int   sidx[TOKB][4];
    __shared__ int   hist[NE];

#define SWZ(tok) ((((tok) >> 1) & 3) << 4)

    const int tid  = threadIdx.x;
    const int lane = tid & 63;
    const int wv   = __builtin_amdgcn_readfirstlane(tid >> 6);   // 0..11
    const int ks   = wv >> 2;        // k-third 0..2
    const int wq   = wv & 3;         // expert group 0..3
    const int lg   = lane >> 4;      // k-quarter 0..3
    const int lr   = lane & 15;
    const int tokBase = blockIdx.x * TOKB;
    const int hbeg = ks * NCHG;      // first global chunk of this k-third

    // W per-lane fragment base (m=0): e = wq*32 + lr, k-off lg*8.
    // m=1 adds 16 experts * 32 halves = 1024 B -> offset:1024 immediate.
    const _Float16* wHp0 = whi + (size_t)((wq * 32 + lr) * 32 + lg * 8);
    const _Float16* wLp0 = wlo + (size_t)((wq * 32 + lr) * 32 + lg * 8);

    // A producer: ks-group's 256 threads stage 64 tok x 32 k per chunk;
    // thread -> (tok, 8-float k-part): 2 dwordx4 per chunk.
    const int gid   = tid & 255;
    const int ptok  = gid >> 2;
    const int ppart = gid & 3;
    const float* aSrc = A + (size_t)(tokBase + ptok) * HID + ppart * 8;
    const int aWr = ptok * 64 + ((ppart * 16) ^ SWZ(ptok));   // swizzled byte off

    // A consumer byte offsets: token n*16+lr, k-quarter lg (same swizzle)
    int aRd[4];
#pragma unroll
    for (int n = 0; n < 4; ++n) {
        const int tok = n * 16 + lr;
        aRd[n] = tok * 64 + ((lg * 16) ^ SWZ(tok));
    }

    // W set: [m*2 + hl] -> 4 half8v = 16 VGPR forced
#define WISSUE(SET, ch) do {                                                   \
    const _Float16* hp_ = wHp0 + (size_t)(ch) * 4096;                          \
    const _Float16* lp_ = wLp0 + (size_t)(ch) * 4096;                          \
    GLOAD(SET[0], hp_);                                                        \
    GLOAD(SET[1], lp_);                                                        \
    GLOAD_O1024(SET[2], hp_);                                                  \
    GLOAD_O1024(SET[3], lp_);                                                  \
} while (0)

    // convert one chunk's A regs (2 float4) -> hi/lo half8, write ring slot
#define CONVA1(AX, AY, SLOT) do {                                              \
    const _Float16 h0=(_Float16)AX.x, h1=(_Float16)AX.y,                       \
                   h2=(_Float16)AX.z, h3=(_Float16)AX.w;                       \
    const _Float16 h4=(_Float16)AY.x, h5=(_Float16)AY.y,                       \
                   h6=(_Float16)AY.z, h7=(_Float16)AY.w;                       \
    const half8v hh = {h0,h1,h2,h3,h4,h5,h6,h7};                               \
    const half8v ll = {(_Float16)(AX.x-(float)h0),(_Float16)(AX.y-(float)h1),  \
                       (_Float16)(AX.z-(float)h2),(_Float16)(AX.w-(float)h3),  \
                       (_Float16)(AY.x-(float)h4),(_Float16)(AY.y-(float)h5),  \
                       (_Float16)(AY.z-(float)h6),(_Float16)(AY.w-(float)h7)}; \
    char* wb_ = smem + ks * 49152 + (SLOT) * 8192 + aWr;                       \
    *reinterpret_cast<half8v*>(wb_)        = hh;                               \
    *reinterpret_cast<half8v*>(wb_ + 4096) = ll;                               \
} while (0)

    // ds_read chunk fragments from ring slot into fh/fl
#define DSREAD(SLOT) do {                                                      \
    const char* b0_ = smem + ks * 49152 + (SLOT) * 8192;                       \
    _Pragma("unroll")                                                          \
    for (int n = 0; n < 4; ++n) {                                              \
        fh[n] = *reinterpret_cast<const half8v*>(b0_ + aRd[n]);                \
        fl[n] = *reinterpret_cast<const half8v*>(b0_ + 4096 + aRd[n]);         \
    }                                                                          \
} while (0)

    // pure-register MFMA cluster (same accumulation order as R0-R4)
#define MFMA24(SET) do {                                                       \
    _Pragma("unroll")                                                          \
    for (int n = 0; n < 4; ++n) {                                              \
        _Pragma("unroll")                                                      \
        for (int m = 0; m < 2; ++m) {                                          \
            acc[m][n] = __builtin_amdgcn_mfma_f32_16x16x32_f16(                \
                SET[m * 2 + 0], fh[n], acc[m][n], 0, 0, 0);                    \
            acc[m][n] = __builtin_amdgcn_mfma_f32_16x16x32_f16(                \
                SET[m * 2 + 1], fh[n], acc[m][n], 0, 0, 0);                    \
            acc[m][n] = __builtin_amdgcn_mfma_f32_16x16x32_f16(                \
                SET[m * 2 + 0], fl[n], acc[m][n], 0, 0, 0);                    \
        }                                                                      \
    }                                                                          \
} while (0)

#define VMC(n) do {                                                            \
    asm volatile("s_waitcnt vmcnt(" #n ")" ::: "memory");                      \
    __builtin_amdgcn_sched_barrier(0);                                         \
} while (0)

#define SB0   __builtin_amdgcn_sched_barrier(0)
#define BAR   do { SB0; __builtin_amdgcn_s_barrier(); SB0; } while (0)
#define LGKM0 do { asm volatile("s_waitcnt lgkmcnt(0)" ::: "memory"); SB0; } while (0)

    f32x4v acc[2][4];
#pragma unroll
    for (int m = 0; m < 2; ++m)
#pragma unroll
        for (int n = 0; n < 4; ++n) acc[m][n] = (f32x4v)0.f;

    half8v wS0[4], wS1[4], wS2[4];
    half8v fh[4], fl[4];
    float4 aR0, aR1, aR2, aR3, aR4, aR5;

    // stage A-group (3 chunks starting at group-local chunk B_) into aR0..aR5
#define ASTAGE(B_) do {                                                        \
    const float* p_ = aSrc + (size_t)(hbeg + (B_)) * BK;                       \
    GLOAD(aR0, p_);      GLOAD(aR1, p_ + 4);                                   \
    GLOAD(aR2, p_ + 32); GLOAD(aR3, p_ + 36);                                  \
    GLOAD(aR4, p_ + 64); GLOAD(aR5, p_ + 68);                                  \
} while (0)

    // ---- cells: chunk c = 3G+j consumes slot (G&1)*3+j with set wSj ----
    // FIFO ledger (steady, G<9):
    //  CELL0: in 12 (W(c),W(c+1),W(c+2)); +A(6) -> 18; VMC(14) retires W(c).
    //  CELL1: in 14+W(c+2 issue)=18; VMC(14) retires W(c+1).
    //  CELL2: in 18; VMC(8) retires W(c+2)+A (CONVA needs A); CONVA g+1.
    // Tail (G=9): VMC(8)/(4)/(0) — drain only in the final 3 cells.
#define CELL0(G, VMN) do {                                                     \
    if ((G) < 9) ASTAGE(3 * (G) + 3);                                          \
    SB0;                                                                       \
    VMC(VMN);                                                                  \
    DSREAD(((G) & 1) * 3 + 0);                                                 \
    BAR;                                                                       \
    LGKM0;                                                                     \
    __builtin_amdgcn_s_setprio(1); MFMA24(wS0); __builtin_amdgcn_s_setprio(0); \
    if (3 * (G) + 3 < NCHG) WISSUE(wS0, hbeg + 3 * (G) + 3);                   \
    BAR;                                                                       \
} while (0)

#define CELL1(G, VMN) do {                                                     \
    VMC(VMN);                                                                  \
    DSREAD(((G) & 1) * 3 + 1);                                                 \
    BAR;                                                                       \
    LGKM0;                                                                     \
    __builtin_amdgcn_s_setprio(1); MFMA24(wS1); __builtin_amdgcn_s_setprio(0); \
    if (3 * (G) + 4 < NCHG) WISSUE(wS1, hbeg + 3 * (G) + 4);                   \
    BAR;                                                                       \
} while (0)

#define CELL2(G, VMN) do {                                                     \
    VMC(VMN);                                                                  \
    if ((G) < 9) {                                                             \
        const int ps_ = (((G) & 1) * 3) ^ 3;   /* slots for group G+1 */       \
        CONVA1(aR0, aR1, ps_ + 0);                                             \
        CONVA1(aR2, aR3, ps_ + 1);                                             \
        CONVA1(aR4, aR5, ps_ + 2);                                             \
    }                                                                          \
    DSREAD(((G) & 1) * 3 + 2);                                                 \
    BAR;                                                                       \
    LGKM0;                                                                     \
    __builtin_amdgcn_s_setprio(1); MFMA24(wS2); __builtin_amdgcn_s_setprio(0); \
    if (3 * (G) + 5 < NCHG) WISSUE(wS2, hbeg + 3 * (G) + 5);                   \
    BAR;                                                                       \
} while (0)

    // prologue: A(g0) + W(0,1,2); VMC(12) retires A only; CONVA slots 0..2
    ASTAGE(0);
    WISSUE(wS0, hbeg + 0);
    WISSUE(wS1, hbeg + 1);
    WISSUE(wS2, hbeg + 2);
    VMC(12);
    CONVA1(aR0, aR1, 0);
    CONVA1(aR2, aR3, 1);
    CONVA1(aR4, aR5, 2);
    LGKM0;
    BAR;

#pragma unroll 1
    for (int g = 0; g < 9; ++g) {
        CELL0(g, 14);
        CELL1(g, 14);
        CELL2(g, 8);
    }
    CELL0(9, 8);
    CELL1(9, 4);
    CELL2(9, 0);

    __syncthreads();   // all ring reads done before epilogue overlay

    // ---------------- epilogue: deterministic 3-way reduction ----------------
    float* P1   = (float*)(smem);            // 64*129*4 = 33024 B (overlay)
    float* P2   = (float*)(smem + 33024);    // 33024 B
    float* cval = (float*)(smem + 66048);    // 64*33*4 = 8448 B
    int*   cidx = (int*)(smem + 74496);      // 8448 B

    if (tid < NE) hist[tid] = 0;

    // ks=1/2 partials -> LDS
    if (ks == 1 || ks == 2) {
        float* P = (ks == 1) ? P1 : P2;
#pragma unroll
        for (int m = 0; m < 2; ++m)
#pragma unroll
            for (int n = 0; n < 4; ++n)
#pragma unroll
                for (int r = 0; r < 4; ++r) {
                    const int e = wq * 32 + m * 16 + lg * 4 + r;
                    const int t = n * 16 + lr;
                    P[t * PSTR + e] = acc[m][n][r];
                }
    }
    __syncthreads();

    // ks=0 combines in fixed order -> logits in P1
    if (ks == 0) {
#pragma unroll
        for (int m = 0; m < 2; ++m)
#pragma unroll
            for (int n = 0; n < 4; ++n)
#pragma unroll
                for (int r = 0; r < 4; ++r) {
                    const int e = wq * 32 + m * 16 + lg * 4 + r;
                    const int t = n * 16 + lr;
                    const int off = t * PSTR + e;
                    P1[off] = ((acc[m][n][r] + P1[off]) + P2[off]) + bias[e];
                }
    }
    __syncthreads();

    // top-4 candidates: 64 tok x 8 groups of 16 experts (threads 0..511)
    if (tid < 512) {
        const int t = tid & 63, g = tid >> 6;
        float v0 = -1e30f, v1 = -1e30f, v2 = -1e30f, v3 = -1e30f;
        int   i0 = 0, i1 = 0, i2 = 0, i3 = 0;
        const int e0 = g * 16;
#pragma unroll 4
        for (int i = 0; i < 16; ++i) {
            const int e = e0 + i;
            const float v = P1[t * PSTR + e];
            if (v > v3) {
                if (v > v2) {
                    v3 = v2; i3 = i2;
                    if (v > v1) {
                        v2 = v1; i2 = i1;
                        if (v > v0) { v1 = v0; i1 = i0; v0 = v; i0 = e; }
                        else        { v1 = v;  i1 = e; }
                    } else { v2 = v; i2 = e; }
                } else { v3 = v; i3 = e; }
            }
        }
        cval[t * 33 + g * 4 + 0] = v0; cidx[t * 33 + g * 4 + 0] = i0;
        cval[t * 33 + g * 4 + 1] = v1; cidx[t * 33 + g * 4 + 1] = i1;
        cval[t * 33 + g * 4 + 2] = v2; cidx[t * 33 + g * 4 + 2] = i2;
        cval[t * 33 + g * 4 + 3] = v3; cidx[t * 33 + g * 4 + 3] = i3;
    }
    __syncthreads();

    if (tid < TOKB) {
        const int t = tid;
        float m0 = -1e30f, m1 = -1e30f, m2 = -1e30f, m3 = -1e30f;
        int   j0 = 0, j1 = 0, j2 = 0, j3 = 0;
#pragma unroll
        for (int q = 0; q < 32; ++q) {   // group-major, ascending e within group
            const float v = cval[t * 33 + q];
            const int   e = cidx[t * 33 + q];
            if (v > m3) {
                if (v > m2) {
                    m3 = m2; j3 = j2;
                    if (v > m1) {
                        m2 = m1; j2 = j1;
                        if (v > m0) { m1 = m0; j1 = j0; m0 = v; j0 = e; }
                        else        { m1 = v;  j1 = e; }
                    } else { m2 = v; j2 = e; }
                } else { m3 = v; j3 = e; }
            }
        }
        const float x1 = expf(m1 - m0), x2 = expf(m2 - m0), x3 = expf(m3 - m0);
        const float inv = 1.f / (1.f + x1 + x2 + x3);
        sval[t][0] = inv;      sidx[t][0] = j0;
        sval[t][1] = x1 * inv; sidx[t][1] = j1;
        sval[t][2] = x2 * inv; sidx[t][2] = j2;
        sval[t][3] = x3 * inv; sidx[t][3] = j3;
        atomicAdd(&hist[j0], 1); atomicAdd(&hist[j1], 1);
        atomicAdd(&hist[j2], 1); atomicAdd(&hist[j3], 1);
    }
    __syncthreads();

    // dense score scatter: 64 tok x 128 exp = 8192 floats, coalesced
    const size_t sBase = (size_t)blockIdx.x * TOKB * NE;
#pragma unroll 4
    for (int it = 0; it < 11; ++it) {
        const int flat = it * 768 + tid;
        if (flat < TOKB * NE) {
            const int t = flat >> 7, e = flat & 127;
            float val = 0.f;
            val = (e == sidx[t][0]) ? sval[t][0] : val;
            val = (e == sidx[t][1]) ? sval[t][1] : val;
            val = (e == sidx[t][2]) ? sval[t][2] : val;
            val = (e == sidx[t][3]) ? sval[t][3] : val;
            scores[sBase + flat] = val;
        }
    }
    // indices as float32: 256 per block
    if (tid < TOKB * 4)
        idxOut[(size_t)blockIdx.x * TOKB * 4 + tid] =
            (float)sidx[tid >> 2][tid & 3];
    if (tid < NE) {
        const int c = hist[tid];
        if (c) atomicAdd(&counts[tid], (float)c);
    }
#undef SWZ
#undef WISSUE
#undef CONVA1
#undef DSREAD
#undef MFMA24
#undef VMC
#undef SB0
#undef BAR
#undef LGKM0
#undef ASTAGE
#undef CELL0
#undef CELL1
#undef CELL2
}

extern "C" void kernel_launch(void* const* d_in, const int* in_sizes, int n_in,
                              void* d_out, int out_size, void* d_ws, size_t ws_size,
                              hipStream_t stream) {
    const float* A = (const float*)d_in[0];   // hidden_states [T, 2880]
    const float* W = (const float*)d_in[1];   // weight [128, 2880]
    const float* B = (const float*)d_in[2];   // bias [128]
    const int T = in_sizes[0] / HID;          // 16384

    float* out = (float*)d_out;
    float* scores = out;                          // [T,128]
    float* idxOut = out + (size_t)T * NE;         // [T,4] as float
    float* counts = idxOut + (size_t)T * 4;       // [128] as float

    _Float16* whi = (_Float16*)d_ws;              // [90][128][32] halves
    _Float16* wlo = whi + (size_t)NE * HID;

    hipMemsetAsync(counts, 0, NE * sizeof(float), stream);

    hipLaunchKernelGGL(prep_w, dim3(NE), dim3(256), 0, stream, W, whi, wlo);
    hipLaunchKernelGGL(fused_router, dim3(T / TOKB), dim3(768), 0, stream,
                       A, whi, wlo, B, scores, idxOut, counts);
}